// Round 14
// baseline (31.616 us; speedup 1.0000x reference)
//
#include <hip/hip_runtime.h>
#include <math.h>

// Problem: x[B=32][N=2048][K=8], W[N][C=32][J=16][K=8], R[N][C]
// out[b][c][j] = squash_j( sum_n softmax_n(R)[n,c] * sum_k W[n,c,j,k]*x[b,n,k] )
// Main accumulates with UNNORMALIZED w = exp(R[n][c]); reduce computes the
// denominators and normalizes before squash. 2 nodes.

#define NN 2048
#define CC 32

__device__ __forceinline__ void g2l16(const float* g, float* l) {
  __builtin_amdgcn_global_load_lds((const __attribute__((address_space(1))) void*)g,
                                   (__attribute__((address_space(3))) void*)l, 16, 0, 0);
}

// ---------- Kernel 1: c-quad contraction; W in LDS ring, x global->VGPR ----------
// grid 512: chunk = bid&63 (32 n), cq = bid>>6. XCD = bid%8 = chunk%8 -> the 8
// cq-blocks of a chunk share an XCD (x slice L2-resident; x reads are 16-lane
// broadcasts served by L1/L2). block 512 = 8 waves; LDS 64KB -> 2 blocks/CU.
// R13 change: x NO LONGER staged in LDS -> LDS instrs drop 24 -> 8 per n per wave
// (the 16 x-reads were 16-fold-broadcast LDS-pipe waste). x is loaded straight to
// VGPRs with cross-slab ping-pong prefetch (p/q) so the vmcnt FIFO stays countable:
//   issue order: S0, xv0, S1, S2 | [xv1] C0 | S3 | [xv2] C1 | [xv3] C2 | C3
//   waits:            vmcnt(4)->C0   vmcnt(2)->C1  vmcnt(0)->C2  vmcnt(0)->C3
// (xv(k+1) issued BEFORE any later stage => waiting on it never force-drains a
//  younger W prefetch; in-compute x loads would sit youngest and cause compiler
//  vmcnt(0) full drains - the R1/R9 failure mode.)
// W: per n 128 granules (2 g2l16) into 3-buf ring; slot S holds source granule
//    g = S ^ bit0(S2^S4) ^ bit1(S3) ^ bit2(S4); read slot = (ci*32+j*2+kh)^(j>>1).
// NO occupancy attributes (R4/R6: VGPR clamp -> ~60MB spill; watch WRITE_SIZE).
__global__ void __launch_bounds__(512) caps_main(const float* __restrict__ x,
                                                 const float* __restrict__ W,
                                                 const float* __restrict__ R,
                                                 float* __restrict__ P) {
  const int bid = blockIdx.x;
  const int cq = bid >> 6;
  const int chunk = bid & 63;
  const int n0 = chunk * 32;
  const int tid = threadIdx.x;
  const int ws = tid >> 6;
  const int lane = tid & 63;
  const int j = lane & 15;
  const int bo = lane >> 4;

  extern __shared__ float smem[];   // 8 waves x 2048 floats = 64 KB
  float* wREG = smem + ws * 2048;   // ring uses first 1536; epilogue uses all 2048
  float* wW = wREG;
  const int nw = n0 + ws * 4;

  // ---- R loads first (oldest queue entries) ----
  float4 rq[4];
#pragma unroll
  for (int nl = 0; nl < 4; ++nl)
    rq[nl] = *(const float4*)(R + (size_t)(nw + nl) * CC + cq * 4);
  __builtin_amdgcn_sched_barrier(0);

  auto stageW = [&](int nl, int buf) {
#pragma unroll
    for (int i = 0; i < 2; ++i) {
      int S = i * 64 + lane;
      int g = S ^ (((S >> 2) ^ (S >> 4)) & 1) ^ (((S >> 3) & 1) << 1) ^ (((S >> 4) & 1) << 2);
      g2l16(W + (size_t)(nw + nl) * 4096 + cq * 512 + g * 4, wW + buf * 512 + i * 256);
    }
  };

  // per-lane x base pointers (8 b values of this lane's bo group)
  const float* xb[8];
#pragma unroll
  for (int bi = 0; bi < 8; ++bi)
    xb[bi] = x + (size_t)(bo * 8 + bi) * (NN * 8) + (size_t)nw * 8;

  // x prefetch: 16 float4 (kh0 -> a[], kh1 -> b[]), compile-time imm offsets
  float4 pa[8], pb[8], qa[8], qb[8];
#define XLOAD(nl, a, b)                                        \
  {                                                            \
    _Pragma("unroll") for (int bi = 0; bi < 8; ++bi) {         \
      a[bi] = *(const float4*)(xb[bi] + (nl) * 8);             \
      b[bi] = *(const float4*)(xb[bi] + (nl) * 8 + 4);         \
    }                                                          \
  }

  // ---- pinned issue order: S0, xv0, S1, S2 ----
  stageW(0, 0);
  __builtin_amdgcn_sched_barrier(0);
  XLOAD(0, pa, pb);
  __builtin_amdgcn_sched_barrier(0);
  stageW(1, 1);
  __builtin_amdgcn_sched_barrier(0);
  stageW(2, 2);
  __builtin_amdgcn_sched_barrier(0);

  // unnormalized routing weights (compiler waits only the older R loads)
  float rv[4][4];
#pragma unroll
  for (int nl = 0; nl < 4; ++nl) {
    rv[nl][0] = expf(rq[nl].x);
    rv[nl][1] = expf(rq[nl].y);
    rv[nl][2] = expf(rq[nl].z);
    rv[nl][3] = expf(rq[nl].w);
  }

  float acc[4][8];
#pragma unroll
  for (int a = 0; a < 4; ++a)
#pragma unroll
    for (int b = 0; b < 8; ++b) acc[a][b] = 0.f;

  const int jsw = j >> 1;

  auto compute = [&](int nl, int buf, const float4* xa, const float4* xv2) {
    const float* Wn = wW + buf * 512;
#pragma unroll
    for (int kh = 0; kh < 2; ++kh) {
      const float4* xv = (kh == 0) ? xa : xv2;
#pragma unroll
      for (int ci = 0; ci < 4; ++ci) {
        int slot = (ci * 32 + j * 2 + kh) ^ jsw;
        float4 wf = *(const float4*)(Wn + slot * 4);
        float rvv = rv[nl][ci];
        float w0 = wf.x * rvv, w1 = wf.y * rvv, w2 = wf.z * rvv, w3 = wf.w * rvv;
#pragma unroll
        for (int bi = 0; bi < 8; ++bi) {
          float a = acc[ci][bi];
          a = fmaf(w0, xv[bi].x, a);
          a = fmaf(w1, xv[bi].y, a);
          a = fmaf(w2, xv[bi].z, a);
          a = fmaf(w3, xv[bi].w, a);
          acc[ci][bi] = a;
        }
      }
    }
  };

  // ---- slab 0: outstanding = [S0, xv0, S1, S2]; need S0+xv0 -> vmcnt(4) ----
  asm volatile("s_waitcnt vmcnt(4)" ::: "memory");
  __builtin_amdgcn_sched_barrier(0);
  XLOAD(1, qa, qb);                                   // xv1 BEFORE S3
  __builtin_amdgcn_sched_barrier(0);
  compute(0, 0, pa, pb);
  asm volatile("s_waitcnt lgkmcnt(0)" ::: "memory");  // buf0 reads retired (WAR)
  __builtin_amdgcn_sched_barrier(0);
  stageW(3, 0);                                       // ring wrap onto buf0
  __builtin_amdgcn_sched_barrier(0);
  // ---- slab 1: queue = [S1, S2, xv1, S3]; need S1+xv1 -> vmcnt(2) ----
  asm volatile("s_waitcnt vmcnt(2)" ::: "memory");
  __builtin_amdgcn_sched_barrier(0);
  XLOAD(2, pa, pb);
  __builtin_amdgcn_sched_barrier(0);
  compute(1, 1, qa, qb);
  // ---- slab 2: queue = [S2, S3, xv2]; need xv2 (youngest) -> vmcnt(0) ----
  asm volatile("s_waitcnt vmcnt(0)" ::: "memory");
  __builtin_amdgcn_sched_barrier(0);
  XLOAD(3, qa, qb);
  __builtin_amdgcn_sched_barrier(0);
  compute(2, 2, pa, pb);
  // ---- slab 3: need xv3 -> vmcnt(0) ----
  asm volatile("s_waitcnt vmcnt(0)" ::: "memory");
  __builtin_amdgcn_sched_barrier(0);
  compute(3, 0, qa, qb);
#undef XLOAD

  // ---- epilogue: dump into own 2048-float region, 1 barrier, block-sum ----
#pragma unroll
  for (int ci = 0; ci < 4; ++ci)
#pragma unroll
    for (int bi = 0; bi < 8; ++bi)
      wREG[(ci * 8 + bi) * 64 + lane] = acc[ci][bi];
  __syncthreads();
  {
    const int t4 = tid * 4;
    float4 ssum = make_float4(0.f, 0.f, 0.f, 0.f);
#pragma unroll
    for (int w = 0; w < 8; ++w) {
      float4 v = *(const float4*)(smem + (size_t)w * 2048 + t4);
      ssum.x += v.x; ssum.y += v.y; ssum.z += v.z; ssum.w += v.w;
    }
    *(float4*)(P + (size_t)bid * 2048 + t4) = ssum;
  }
}

// ---------- Kernel 2: per-c denominator + float4 cross-chunk reduce + squash ----------
// 32 blocks (one per c) x 128 threads. t = b*4 + jq. (R13-verbatim)
__global__ void caps_reduce(const float* __restrict__ P, const float* __restrict__ R,
                            float* __restrict__ out) {
  const int c = blockIdx.x;
  const int t = threadIdx.x;
  const int b = t >> 2, jq = t & 3;

  __shared__ float red[2];
  {
    float s = 0.f;
#pragma unroll
    for (int i = 0; i < 16; ++i)
      s += expf(R[(size_t)(t + i * 128) * CC + c]);
#pragma unroll
    for (int d = 32; d >= 1; d >>= 1) s += __shfl_xor(s, d, 64);
    if ((t & 63) == 0) red[t >> 6] = s;
  }
  __syncthreads();
  const float inv = 1.0f / (red[0] + red[1]);

  const int cq = c >> 2, ci = c & 3;
  const int bo = b >> 3, bi = b & 7;
  const int cell = (ci * 8 + bi) * 64 + bo * 16 + jq * 4;
  const float* Pq = P + (size_t)cq * 64 * 2048 + cell;

  float4 s4 = make_float4(0.f, 0.f, 0.f, 0.f);
#pragma unroll 16
  for (int ch = 0; ch < 64; ++ch) {
    float4 v = *(const float4*)(Pq + (size_t)ch * 2048);
    s4.x += v.x; s4.y += v.y; s4.z += v.z; s4.w += v.w;
  }
  s4.x *= inv; s4.y *= inv; s4.z *= inv; s4.w *= inv;

  float sq = s4.x * s4.x + s4.y * s4.y + s4.z * s4.z + s4.w * s4.w;
  sq += __shfl_xor(sq, 1, 4);
  sq += __shfl_xor(sq, 2, 4);
  float ss = sq + 1e-7f;
  float scale = sqrtf(ss) / (1.0f + ss);
  s4.x *= scale; s4.y *= scale; s4.z *= scale; s4.w *= scale;

  *(float4*)(out + (size_t)b * 512 + c * 16 + jq * 4) = s4;
}

extern "C" void kernel_launch(void* const* d_in, const int* in_sizes, int n_in,
                              void* d_out, int out_size, void* d_ws, size_t ws_size,
                              hipStream_t stream) {
  const float* x = (const float*)d_in[0];   // 32*2048*8
  const float* W = (const float*)d_in[1];   // 2048*32*16*8
  const float* R = (const float*)d_in[2];   // 2048*32
  float* out = (float*)d_out;               // 32*32*16
  float* P = (float*)d_ws;                  // 512*2048 floats (4 MB)

  hipFuncSetAttribute((const void*)caps_main,
                      hipFuncAttributeMaxDynamicSharedMemorySize, 65536);

  caps_main<<<512, 512, 65536, stream>>>(x, W, R, P);
  caps_reduce<<<32, 128, 0, stream>>>(P, R, out);
}